// Round 1
// baseline (3101.916 us; speedup 1.0000x reference)
//
#include <hip/hip_runtime.h>

// GCN forward: h1=relu(Agg(x@W1)+b1); h2=relu(Agg(h1@W2)+b2); out = meanpool(h2)@Wfc+bfc
// Agg(h)[i] = sum_{e: dst[e]=i} h[src[e]]*dinv[src]*dinv[dst] + h[i]*dinv[i]^2
// deg = in-degree(dst) + 1 (self loop), dinv = rsqrt(deg)

constexpr int IN_DIM  = 128;
constexpr int HID     = 256;
constexpr int HID2    = 128;
constexpr int OUT_DIM = 4;
constexpr int NGRAPH  = 64;

__global__ void deg_init_kernel(float* __restrict__ deg, int n) {
    int i = blockIdx.x * blockDim.x + threadIdx.x;
    if (i < n) deg[i] = 1.0f;   // self-loop
}

__global__ void deg_count_kernel(const int* __restrict__ dst, float* __restrict__ deg, int E) {
    int i = blockIdx.x * blockDim.x + threadIdx.x;
    if (i < E) atomicAdd(&deg[dst[i]], 1.0f);
}

__global__ void dinv_kernel(float* __restrict__ deg, int n) {
    int i = blockIdx.x * blockDim.x + threadIdx.x;
    if (i < n) deg[i] = rsqrtf(deg[i]);   // in place: deg -> dinv
}

// C[M,N] = A[M,K] @ B[K,N];  Cself[r,c] = C[r,c] * dinv[r]^2  (self-loop init of agg)
// 64x64 block tile, 256 threads, 4x4 microtile, K-chunks of 16.
template <int K>
__launch_bounds__(256)
__global__ void gemm_self_kernel(const float* __restrict__ A, const float* __restrict__ B,
                                 const float* __restrict__ dinv,
                                 float* __restrict__ C, float* __restrict__ Cself,
                                 int M, int N) {
    __shared__ float As[16][64];   // [kk][m]
    __shared__ float Bs[16][64];   // [kk][n]

    const int tid = threadIdx.x;
    const int tm = tid & 15;       // micro-row group
    const int tn = tid >> 4;       // micro-col group
    const int row0 = blockIdx.y * 64;
    const int col0 = blockIdx.x * 64;

    // staging indices
    const int lm = tid >> 2;          // 0..63  A-row in tile
    const int lk = (tid & 3) * 4;     // 0,4,8,12
    const int bk = tid >> 4;          // 0..15  B k-row
    const int bn = (tid & 15) * 4;    // 0..60

    float acc[4][4] = {};

    for (int k0 = 0; k0 < K; k0 += 16) {
        int arow = row0 + lm;
        float4 a4 = make_float4(0.f, 0.f, 0.f, 0.f);
        if (arow < M) a4 = *(const float4*)(A + (size_t)arow * K + k0 + lk);
        As[lk + 0][lm] = a4.x;
        As[lk + 1][lm] = a4.y;
        As[lk + 2][lm] = a4.z;
        As[lk + 3][lm] = a4.w;

        float4 b4 = *(const float4*)(B + (size_t)(k0 + bk) * N + col0 + bn);
        *(float4*)&Bs[bk][bn] = b4;
        __syncthreads();

#pragma unroll
        for (int kk = 0; kk < 16; ++kk) {
            float4 a = *(const float4*)&As[kk][tm * 4];
            float4 b = *(const float4*)&Bs[kk][tn * 4];
            float av[4] = {a.x, a.y, a.z, a.w};
            float bv[4] = {b.x, b.y, b.z, b.w};
#pragma unroll
            for (int i = 0; i < 4; ++i)
#pragma unroll
                for (int j = 0; j < 4; ++j)
                    acc[i][j] = fmaf(av[i], bv[j], acc[i][j]);
        }
        __syncthreads();
    }

#pragma unroll
    for (int i = 0; i < 4; ++i) {
        int r = row0 + tm * 4 + i;
        if (r < M) {
            float4 v = make_float4(acc[i][0], acc[i][1], acc[i][2], acc[i][3]);
            *(float4*)(C + (size_t)r * N + col0 + tn * 4) = v;
            float dv = dinv[r];
            float d2 = dv * dv;
            float4 w = make_float4(v.x * d2, v.y * d2, v.z * d2, v.w * d2);
            *(float4*)(Cself + (size_t)r * N + col0 + tn * 4) = w;
        }
    }
}

// One wave per edge: gather h[src]*norm, scatter-add into agg[dst].
template <int D>
__global__ void edge_agg_kernel(const float* __restrict__ h, const float* __restrict__ dinv,
                                const int* __restrict__ src, const int* __restrict__ dst,
                                float* __restrict__ agg, int E) {
    int t = blockIdx.x * blockDim.x + threadIdx.x;
    int e = t >> 6;
    int lane = t & 63;
    if (e >= E) return;
    int s = src[e], d = dst[e];
    float norm = dinv[s] * dinv[d];
    if constexpr (D == 256) {
        float4 v = *(const float4*)(h + (size_t)s * D + lane * 4);
        float* o = agg + (size_t)d * D + lane * 4;
        atomicAdd(o + 0, v.x * norm);
        atomicAdd(o + 1, v.y * norm);
        atomicAdd(o + 2, v.z * norm);
        atomicAdd(o + 3, v.w * norm);
    } else {  // D == 128
        float2 v = *(const float2*)(h + (size_t)s * D + lane * 2);
        float* o = agg + (size_t)d * D + lane * 2;
        atomicAdd(o + 0, v.x * norm);
        atomicAdd(o + 1, v.y * norm);
    }
}

template <int D>
__global__ void bias_relu_kernel(float* __restrict__ h, const float* __restrict__ bias, int total4) {
    int i = blockIdx.x * blockDim.x + threadIdx.x;
    if (i >= total4) return;
    float4 v = ((float4*)h)[i];
    int c = (i * 4) & (D - 1);
    float4 b = *(const float4*)(bias + c);
    v.x = fmaxf(v.x + b.x, 0.f);
    v.y = fmaxf(v.y + b.y, 0.f);
    v.z = fmaxf(v.z + b.z, 0.f);
    v.w = fmaxf(v.w + b.w, 0.f);
    ((float4*)h)[i] = v;
}

__device__ __forceinline__ int lower_bound_i(const int* __restrict__ a, int n, int key) {
    int lo = 0, hi = n;
    while (lo < hi) {
        int mid = (lo + hi) >> 1;
        if (a[mid] < key) lo = mid + 1; else hi = mid;
    }
    return lo;
}

// batch is sorted: block g sums its contiguous node segment. Deterministic, no atomics.
__global__ void pool_kernel(const float* __restrict__ h, const int* __restrict__ batch,
                            float* __restrict__ pool, float* __restrict__ cnt, int N) {
    int g = blockIdx.x;
    int c = threadIdx.x;  // 128 threads = HID2 dims
    int lo = lower_bound_i(batch, N, g);
    int hi = lower_bound_i(batch, N, g + 1);
    float acc = 0.f;
    for (int i = lo; i < hi; ++i) acc += h[(size_t)i * HID2 + c];
    pool[g * HID2 + c] = acc;
    if (c == 0) cnt[g] = (float)(hi - lo);
}

__global__ void fc_kernel(const float* __restrict__ pool, const float* __restrict__ cnt,
                          const float* __restrict__ Wfc, const float* __restrict__ bfc,
                          float* __restrict__ out) {
    int t = threadIdx.x;  // 256 = 64 graphs * 4 outputs
    int g = t >> 2, o = t & 3;
    float acc = 0.f;
#pragma unroll 8
    for (int c = 0; c < HID2; ++c)
        acc = fmaf(pool[g * HID2 + c], Wfc[c * OUT_DIM + o], acc);
    float inv = 1.0f / fmaxf(cnt[g], 1.0f);
    out[g * OUT_DIM + o] = acc * inv + bfc[o];
}

extern "C" void kernel_launch(void* const* d_in, const int* in_sizes, int n_in,
                              void* d_out, int out_size, void* d_ws, size_t ws_size,
                              hipStream_t stream) {
    const float* x   = (const float*)d_in[0];
    const int* src   = (const int*)d_in[1];
    const int* dst   = (const int*)d_in[2];
    const int* batch = (const int*)d_in[3];
    const float* W1  = (const float*)d_in[4];
    const float* b1  = (const float*)d_in[5];
    const float* W2  = (const float*)d_in[6];
    const float* b2  = (const float*)d_in[7];
    const float* Wfc = (const float*)d_in[8];
    const float* bfc = (const float*)d_in[9];
    float* out = (float*)d_out;

    const int N = in_sizes[0] / IN_DIM;  // 50000
    const int E = in_sizes[1];           // 640000

    // workspace layout (~103 MB)
    char* ws = (char*)d_ws;
    float* dinv = (float*)ws;                              // N
    size_t off = (((size_t)N * 4) + 255) & ~(size_t)255;
    float* h1   = (float*)(ws + off);                      // N*HID  (region A)
    float* h2   = h1;                                      // N*HID2 (reuses region A)
    float* agg2 = h1 + (size_t)N * HID2;                   // N*HID2 (region A, 2nd half)
    float* agg1 = h1 + (size_t)N * HID;                    // N*HID  (region B)
    float* pool = agg1 + (size_t)N * HID;                  // NGRAPH*HID2
    float* cnt  = pool + NGRAPH * HID2;                    // NGRAPH

    // degrees -> dinv
    deg_init_kernel<<<(N + 255) / 256, 256, 0, stream>>>(dinv, N);
    deg_count_kernel<<<(E + 255) / 256, 256, 0, stream>>>(dst, dinv, E);
    dinv_kernel<<<(N + 255) / 256, 256, 0, stream>>>(dinv, N);

    // layer 1: h1 = x@W1 ; agg1 = h1*dinv^2 ; agg1 += edges ; relu(+b1)
    gemm_self_kernel<IN_DIM><<<dim3(HID / 64, (N + 63) / 64), 256, 0, stream>>>(
        x, W1, dinv, h1, agg1, N, HID);
    edge_agg_kernel<HID><<<(E + 3) / 4, 256, 0, stream>>>(h1, dinv, src, dst, agg1, E);
    bias_relu_kernel<HID><<<((N * HID / 4) + 255) / 256, 256, 0, stream>>>(
        agg1, b1, N * HID / 4);

    // layer 2: h2 = agg1@W2 ; agg2 = h2*dinv^2 ; agg2 += edges ; relu(+b2)
    gemm_self_kernel<HID><<<dim3(HID2 / 64, (N + 63) / 64), 256, 0, stream>>>(
        agg1, W2, dinv, h2, agg2, N, HID2);
    edge_agg_kernel<HID2><<<(E + 3) / 4, 256, 0, stream>>>(h2, dinv, src, dst, agg2, E);
    bias_relu_kernel<HID2><<<((N * HID2 / 4) + 255) / 256, 256, 0, stream>>>(
        agg2, b2, N * HID2 / 4);

    // pool + fc
    pool_kernel<<<NGRAPH, HID2, 0, stream>>>(agg2, batch, pool, cnt, N);
    fc_kernel<<<1, NGRAPH * OUT_DIM, 0, stream>>>(pool, cnt, Wfc, bfc, out);
}

// Round 2
// 629.369 us; speedup vs baseline: 4.9286x; 4.9286x over previous
//
#include <hip/hip_runtime.h>

// GCN forward, gather-based aggregation (no float atomics on the feature matrix).
// h1 = x@W1; a1 = relu(GatherAgg(h1) + b1); h2 = a1@W2; a2 = relu(GatherAgg(h2) + b2);
// out = meanpool(a2)@Wfc + bfc
// GatherAgg(h)[d] = sum_{e: dst[e]=d} h[src[e]]*dinv[src]*dinv[d] + h[d]*dinv[d]^2
// CSR-by-dst built per call: histogram -> block scan -> scatter src indices.

constexpr int IN_DIM  = 128;
constexpr int HID     = 256;
constexpr int HID2    = 128;
constexpr int OUT_DIM = 4;
constexpr int NGRAPH  = 64;

// ---------------- CSR build ----------------

__global__ void hist_kernel(const int* __restrict__ dst, int* __restrict__ count, int E) {
    int i = blockIdx.x * blockDim.x + threadIdx.x;
    if (i < E) atomicAdd(&count[dst[i]], 1);
}

// per-block inclusive scan of counts; emit block totals
__global__ void scan1_kernel(const int* __restrict__ count, int* __restrict__ bsums, int N) {
    __shared__ int s[256];
    int t = threadIdx.x, i = blockIdx.x * 256 + t;
    int v = (i < N) ? count[i] : 0;
    s[t] = v; __syncthreads();
    for (int o = 1; o < 256; o <<= 1) {
        int x = (t >= o) ? s[t - o] : 0;
        __syncthreads(); s[t] += x; __syncthreads();
    }
    if (t == 255) bsums[blockIdx.x] = s[255];
}

// exclusive scan of block sums (nb <= 256)
__global__ void scan2_kernel(int* __restrict__ bsums, int nb) {
    __shared__ int s[256];
    int t = threadIdx.x;
    int v = (t < nb) ? bsums[t] : 0;
    s[t] = v; __syncthreads();
    for (int o = 1; o < 256; o <<= 1) {
        int x = (t >= o) ? s[t - o] : 0;
        __syncthreads(); s[t] += x; __syncthreads();
    }
    if (t < nb) bsums[t] = s[t] - v;
}

// final: rowptr/cursor = exclusive scan, dinv = rsqrt(deg+1)
__global__ void scan3_kernel(const int* __restrict__ count, const int* __restrict__ bsums,
                             int* __restrict__ rowptr, int* __restrict__ cursor,
                             float* __restrict__ dinv, int N, int E) {
    __shared__ int s[256];
    int t = threadIdx.x, i = blockIdx.x * 256 + t;
    int v = (i < N) ? count[i] : 0;
    s[t] = v; __syncthreads();
    for (int o = 1; o < 256; o <<= 1) {
        int x = (t >= o) ? s[t - o] : 0;
        __syncthreads(); s[t] += x; __syncthreads();
    }
    if (i < N) {
        int ex = bsums[blockIdx.x] + s[t] - v;
        rowptr[i] = ex;
        cursor[i] = ex;
        dinv[i] = rsqrtf((float)v + 1.0f);
        if (i == 0) rowptr[N] = E;
    }
}

__global__ void scatter_kernel(const int* __restrict__ src, const int* __restrict__ dst,
                               int* __restrict__ cursor, int* __restrict__ csr, int E) {
    int e = blockIdx.x * blockDim.x + threadIdx.x;
    if (e < E) {
        int p = atomicAdd(&cursor[dst[e]], 1);
        csr[p] = src[e];
    }
}

// ---------------- GEMM (f32, 64x64 tile, 4x4 microtile) ----------------

template <int K>
__launch_bounds__(256)
__global__ void gemm_kernel(const float* __restrict__ A, const float* __restrict__ B,
                            float* __restrict__ C, int M, int N) {
    __shared__ float As[16][64];   // [kk][m]
    __shared__ float Bs[16][64];   // [kk][n]

    const int tid = threadIdx.x;
    const int tm = tid & 15;
    const int tn = tid >> 4;
    const int row0 = blockIdx.y * 64;
    const int col0 = blockIdx.x * 64;

    const int lm = tid >> 2;
    const int lk = (tid & 3) * 4;
    const int bk = tid >> 4;
    const int bn = (tid & 15) * 4;

    float acc[4][4] = {};

    for (int k0 = 0; k0 < K; k0 += 16) {
        int arow = row0 + lm;
        float4 a4 = make_float4(0.f, 0.f, 0.f, 0.f);
        if (arow < M) a4 = *(const float4*)(A + (size_t)arow * K + k0 + lk);
        As[lk + 0][lm] = a4.x;
        As[lk + 1][lm] = a4.y;
        As[lk + 2][lm] = a4.z;
        As[lk + 3][lm] = a4.w;

        float4 b4 = *(const float4*)(B + (size_t)(k0 + bk) * N + col0 + bn);
        *(float4*)&Bs[bk][bn] = b4;
        __syncthreads();

#pragma unroll
        for (int kk = 0; kk < 16; ++kk) {
            float4 a = *(const float4*)&As[kk][tm * 4];
            float4 b = *(const float4*)&Bs[kk][tn * 4];
            float av[4] = {a.x, a.y, a.z, a.w};
            float bv[4] = {b.x, b.y, b.z, b.w};
#pragma unroll
            for (int i = 0; i < 4; ++i)
#pragma unroll
                for (int j = 0; j < 4; ++j)
                    acc[i][j] = fmaf(av[i], bv[j], acc[i][j]);
        }
        __syncthreads();
    }

#pragma unroll
    for (int i = 0; i < 4; ++i) {
        int r = row0 + tm * 4 + i;
        if (r < M)
            *(float4*)(C + (size_t)r * N + col0 + tn * 4) =
                make_float4(acc[i][0], acc[i][1], acc[i][2], acc[i][3]);
    }
}

// ---------------- gather aggregation (one wave per dst node) ----------------
// out[d] = relu( sum_{j in row d} h[csr[j]] * dinv[csr[j]]*dinv[d]  +  h[d]*dinv[d]^2 + bias )

template <int D>
__launch_bounds__(256)
__global__ void agg_gather_kernel(const float* __restrict__ h, const float* __restrict__ dinv,
                                  const int* __restrict__ rowptr, const int* __restrict__ csr,
                                  const float* __restrict__ bias, float* __restrict__ out, int N) {
    int wid = (blockIdx.x * blockDim.x + threadIdx.x) >> 6;  // node id
    int lane = threadIdx.x & 63;
    if (wid >= N) return;
    int lo = rowptr[wid], hi = rowptr[wid + 1];
    float dd = dinv[wid];

    if constexpr (D == 256) {
        const float4* hp = (const float4*)h;           // 64 float4 per row
        float4 acc = hp[(size_t)wid * 64 + lane];
        float sc = dd * dd;
        acc.x *= sc; acc.y *= sc; acc.z *= sc; acc.w *= sc;
        for (int j = lo; j < hi; ++j) {
            int s = csr[j];
            float nm = dinv[s] * dd;
            float4 v = hp[(size_t)s * 64 + lane];
            acc.x = fmaf(v.x, nm, acc.x);
            acc.y = fmaf(v.y, nm, acc.y);
            acc.z = fmaf(v.z, nm, acc.z);
            acc.w = fmaf(v.w, nm, acc.w);
        }
        float4 b = ((const float4*)bias)[lane];
        acc.x = fmaxf(acc.x + b.x, 0.f);
        acc.y = fmaxf(acc.y + b.y, 0.f);
        acc.z = fmaxf(acc.z + b.z, 0.f);
        acc.w = fmaxf(acc.w + b.w, 0.f);
        ((float4*)out)[(size_t)wid * 64 + lane] = acc;
    } else {  // D == 128
        const float2* hp = (const float2*)h;           // 64 float2 per row
        float2 acc = hp[(size_t)wid * 64 + lane];
        float sc = dd * dd;
        acc.x *= sc; acc.y *= sc;
        for (int j = lo; j < hi; ++j) {
            int s = csr[j];
            float nm = dinv[s] * dd;
            float2 v = hp[(size_t)s * 64 + lane];
            acc.x = fmaf(v.x, nm, acc.x);
            acc.y = fmaf(v.y, nm, acc.y);
        }
        float2 b = ((const float2*)bias)[lane];
        acc.x = fmaxf(acc.x + b.x, 0.f);
        acc.y = fmaxf(acc.y + b.y, 0.f);
        ((float2*)out)[(size_t)wid * 64 + lane] = acc;
    }
}

// ---------------- pool + fc ----------------

__device__ __forceinline__ int lower_bound_i(const int* __restrict__ a, int n, int key) {
    int lo = 0, hi = n;
    while (lo < hi) {
        int mid = (lo + hi) >> 1;
        if (a[mid] < key) lo = mid + 1; else hi = mid;
    }
    return lo;
}

__global__ void pool_kernel(const float* __restrict__ h, const int* __restrict__ batch,
                            float* __restrict__ pool, float* __restrict__ cnt, int N) {
    int g = blockIdx.x;
    int c = threadIdx.x;  // 128 threads = HID2 dims
    int lo = lower_bound_i(batch, N, g);
    int hi = lower_bound_i(batch, N, g + 1);
    float acc = 0.f;
    for (int i = lo; i < hi; ++i) acc += h[(size_t)i * HID2 + c];
    pool[g * HID2 + c] = acc;
    if (c == 0) cnt[g] = (float)(hi - lo);
}

__global__ void fc_kernel(const float* __restrict__ pool, const float* __restrict__ cnt,
                          const float* __restrict__ Wfc, const float* __restrict__ bfc,
                          float* __restrict__ out) {
    int t = threadIdx.x;  // 256 = 64 graphs * 4 outputs
    int g = t >> 2, o = t & 3;
    float acc = 0.f;
#pragma unroll 8
    for (int c = 0; c < HID2; ++c)
        acc = fmaf(pool[g * HID2 + c], Wfc[c * OUT_DIM + o], acc);
    float inv = 1.0f / fmaxf(cnt[g], 1.0f);
    out[g * OUT_DIM + o] = acc * inv + bfc[o];
}

extern "C" void kernel_launch(void* const* d_in, const int* in_sizes, int n_in,
                              void* d_out, int out_size, void* d_ws, size_t ws_size,
                              hipStream_t stream) {
    const float* x   = (const float*)d_in[0];
    const int* src   = (const int*)d_in[1];
    const int* dst   = (const int*)d_in[2];
    const int* batch = (const int*)d_in[3];
    const float* W1  = (const float*)d_in[4];
    const float* b1  = (const float*)d_in[5];
    const float* W2  = (const float*)d_in[6];
    const float* b2  = (const float*)d_in[7];
    const float* Wfc = (const float*)d_in[8];
    const float* bfc = (const float*)d_in[9];
    float* out = (float*)d_out;

    const int N = in_sizes[0] / IN_DIM;  // 50000
    const int E = in_sizes[1];           // 640000
    const int NB = (N + 255) / 256;      // scan blocks (196)

    // ---- workspace layout ----
    char* ws = (char*)d_ws;
    size_t off = 0;
    auto alloc = [&](size_t bytes) {
        char* p = ws + off;
        off = (off + bytes + 255) & ~(size_t)255;
        return p;
    };
    float* dinv   = (float*)alloc((size_t)N * 4);
    int*   count  = (int*)  alloc((size_t)N * 4);
    int*   cursor = (int*)  alloc((size_t)N * 4);
    int*   rowptr = (int*)  alloc((size_t)(N + 1) * 4);
    int*   bsums  = (int*)  alloc(256 * 4);
    int*   csr    = (int*)  alloc((size_t)E * 4);
    float* h1     = (float*)alloc((size_t)N * HID * 4);   // reused as h2 (N*HID2)
    float* a1     = (float*)alloc((size_t)N * HID * 4);   // reused as a2 (N*HID2)
    float* pool   = (float*)alloc((size_t)NGRAPH * HID2 * 4);
    float* cnt    = (float*)alloc((size_t)NGRAPH * 4);
    float* h2 = h1;
    float* a2 = a1;

    // ---- CSR build (once; serves both layers) ----
    hipMemsetAsync(count, 0, (size_t)N * 4, stream);
    hist_kernel<<<(E + 255) / 256, 256, 0, stream>>>(dst, count, E);
    scan1_kernel<<<NB, 256, 0, stream>>>(count, bsums, N);
    scan2_kernel<<<1, 256, 0, stream>>>(bsums, NB);
    scan3_kernel<<<NB, 256, 0, stream>>>(count, bsums, rowptr, cursor, dinv, N, E);
    scatter_kernel<<<(E + 255) / 256, 256, 0, stream>>>(src, dst, cursor, csr, E);

    // ---- layer 1 ----
    gemm_kernel<IN_DIM><<<dim3(HID / 64, (N + 63) / 64), 256, 0, stream>>>(x, W1, h1, N, HID);
    agg_gather_kernel<HID><<<(N + 3) / 4, 256, 0, stream>>>(h1, dinv, rowptr, csr, b1, a1, N);

    // ---- layer 2 ----
    gemm_kernel<HID><<<dim3(HID2 / 64, (N + 63) / 64), 256, 0, stream>>>(a1, W2, h2, N, HID2);
    agg_gather_kernel<HID2><<<(N + 3) / 4, 256, 0, stream>>>(h2, dinv, rowptr, csr, b2, a2, N);

    // ---- pool + fc ----
    pool_kernel<<<NGRAPH, HID2, 0, stream>>>(a2, batch, pool, cnt, N);
    fc_kernel<<<1, NGRAPH * OUT_DIM, 0, stream>>>(pool, cnt, Wfc, bfc, out);
}

// Round 3
// 455.594 us; speedup vs baseline: 6.8085x; 1.3814x over previous
//
#include <hip/hip_runtime.h>

// GCN forward, gather-based aggregation (no float atomics on the feature matrix).
// h1 = x@W1; a1 = relu(GatherAgg(h1) + b1); h2 = a1@W2; a2 = relu(GatherAgg(h2) + b2);
// out = meanpool(a2)@Wfc + bfc
// GatherAgg(h)[d] = sum_{e: dst[e]=d} h[src[e]]*dinv[src]*dinv[d] + h[d]*dinv[d]^2
// CSR-by-dst built per call: histogram -> block scan -> scatter src indices.

constexpr int IN_DIM  = 128;
constexpr int HID     = 256;
constexpr int HID2    = 128;
constexpr int OUT_DIM = 4;
constexpr int NGRAPH  = 64;
constexpr int PCH     = 64;   // nodes per pool block

// ---------------- CSR build ----------------

__global__ void hist_kernel(const int* __restrict__ dst, int* __restrict__ count, int E) {
    int i = blockIdx.x * blockDim.x + threadIdx.x;
    if (i < E) atomicAdd(&count[dst[i]], 1);
}

// per-block inclusive scan of counts; emit block totals
__global__ void scan1_kernel(const int* __restrict__ count, int* __restrict__ bsums, int N) {
    __shared__ int s[256];
    int t = threadIdx.x, i = blockIdx.x * 256 + t;
    int v = (i < N) ? count[i] : 0;
    s[t] = v; __syncthreads();
    for (int o = 1; o < 256; o <<= 1) {
        int x = (t >= o) ? s[t - o] : 0;
        __syncthreads(); s[t] += x; __syncthreads();
    }
    if (t == 255) bsums[blockIdx.x] = s[255];
}

// exclusive scan of block sums (nb <= 256)
__global__ void scan2_kernel(int* __restrict__ bsums, int nb) {
    __shared__ int s[256];
    int t = threadIdx.x;
    int v = (t < nb) ? bsums[t] : 0;
    s[t] = v; __syncthreads();
    for (int o = 1; o < 256; o <<= 1) {
        int x = (t >= o) ? s[t - o] : 0;
        __syncthreads(); s[t] += x; __syncthreads();
    }
    if (t < nb) bsums[t] = s[t] - v;
}

// final: rowptr/cursor = exclusive scan, dinv = rsqrt(deg+1)
__global__ void scan3_kernel(const int* __restrict__ count, const int* __restrict__ bsums,
                             int* __restrict__ rowptr, int* __restrict__ cursor,
                             float* __restrict__ dinv, int N, int E) {
    __shared__ int s[256];
    int t = threadIdx.x, i = blockIdx.x * 256 + t;
    int v = (i < N) ? count[i] : 0;
    s[t] = v; __syncthreads();
    for (int o = 1; o < 256; o <<= 1) {
        int x = (t >= o) ? s[t - o] : 0;
        __syncthreads(); s[t] += x; __syncthreads();
    }
    if (i < N) {
        int ex = bsums[blockIdx.x] + s[t] - v;
        rowptr[i] = ex;
        cursor[i] = ex;
        dinv[i] = rsqrtf((float)v + 1.0f);
        if (i == 0) rowptr[N] = E;
    }
}

__global__ void scatter_kernel(const int* __restrict__ src, const int* __restrict__ dst,
                               int* __restrict__ cursor, int* __restrict__ csr, int E) {
    int e = blockIdx.x * blockDim.x + threadIdx.x;
    if (e < E) {
        int p = atomicAdd(&cursor[dst[e]], 1);
        csr[p] = src[e];
    }
}

// ---------------- GEMM (f32, 64x64 tile, 4x4 microtile) ----------------

template <int K>
__launch_bounds__(256)
__global__ void gemm_kernel(const float* __restrict__ A, const float* __restrict__ B,
                            float* __restrict__ C, int M, int N) {
    __shared__ float As[16][64];   // [kk][m]
    __shared__ float Bs[16][64];   // [kk][n]

    const int tid = threadIdx.x;
    const int tm = tid & 15;
    const int tn = tid >> 4;
    const int row0 = blockIdx.y * 64;
    const int col0 = blockIdx.x * 64;

    const int lm = tid >> 2;
    const int lk = (tid & 3) * 4;
    const int bk = tid >> 4;
    const int bn = (tid & 15) * 4;

    float acc[4][4] = {};

    for (int k0 = 0; k0 < K; k0 += 16) {
        int arow = row0 + lm;
        float4 a4 = make_float4(0.f, 0.f, 0.f, 0.f);
        if (arow < M) a4 = *(const float4*)(A + (size_t)arow * K + k0 + lk);
        As[lk + 0][lm] = a4.x;
        As[lk + 1][lm] = a4.y;
        As[lk + 2][lm] = a4.z;
        As[lk + 3][lm] = a4.w;

        float4 b4 = *(const float4*)(B + (size_t)(k0 + bk) * N + col0 + bn);
        *(float4*)&Bs[bk][bn] = b4;
        __syncthreads();

#pragma unroll
        for (int kk = 0; kk < 16; ++kk) {
            float4 a = *(const float4*)&As[kk][tm * 4];
            float4 b = *(const float4*)&Bs[kk][tn * 4];
            float av[4] = {a.x, a.y, a.z, a.w};
            float bv[4] = {b.x, b.y, b.z, b.w};
#pragma unroll
            for (int i = 0; i < 4; ++i)
#pragma unroll
                for (int j = 0; j < 4; ++j)
                    acc[i][j] = fmaf(av[i], bv[j], acc[i][j]);
        }
        __syncthreads();
    }

#pragma unroll
    for (int i = 0; i < 4; ++i) {
        int r = row0 + tm * 4 + i;
        if (r < M)
            *(float4*)(C + (size_t)r * N + col0 + tn * 4) =
                make_float4(acc[i][0], acc[i][1], acc[i][2], acc[i][3]);
    }
}

// ---------------- gather aggregation (one wave per dst node) ----------------
// out[d] = relu( sum_{j in row d} h[csr[j]] * dinv[csr[j]]*dinv[d]  +  h[d]*dinv[d]^2 + bias )

template <int D>
__launch_bounds__(256)
__global__ void agg_gather_kernel(const float* __restrict__ h, const float* __restrict__ dinv,
                                  const int* __restrict__ rowptr, const int* __restrict__ csr,
                                  const float* __restrict__ bias, float* __restrict__ out, int N) {
    int wid = (blockIdx.x * blockDim.x + threadIdx.x) >> 6;  // node id
    int lane = threadIdx.x & 63;
    if (wid >= N) return;
    int lo = rowptr[wid], hi = rowptr[wid + 1];
    float dd = dinv[wid];

    if constexpr (D == 256) {
        const float4* hp = (const float4*)h;           // 64 float4 per row
        float4 acc = hp[(size_t)wid * 64 + lane];
        float sc = dd * dd;
        acc.x *= sc; acc.y *= sc; acc.z *= sc; acc.w *= sc;
        for (int j = lo; j < hi; ++j) {
            int s = csr[j];
            float nm = dinv[s] * dd;
            float4 v = hp[(size_t)s * 64 + lane];
            acc.x = fmaf(v.x, nm, acc.x);
            acc.y = fmaf(v.y, nm, acc.y);
            acc.z = fmaf(v.z, nm, acc.z);
            acc.w = fmaf(v.w, nm, acc.w);
        }
        float4 b = ((const float4*)bias)[lane];
        acc.x = fmaxf(acc.x + b.x, 0.f);
        acc.y = fmaxf(acc.y + b.y, 0.f);
        acc.z = fmaxf(acc.z + b.z, 0.f);
        acc.w = fmaxf(acc.w + b.w, 0.f);
        ((float4*)out)[(size_t)wid * 64 + lane] = acc;
    } else {  // D == 128
        const float2* hp = (const float2*)h;           // 64 float2 per row
        float2 acc = hp[(size_t)wid * 64 + lane];
        float sc = dd * dd;
        acc.x *= sc; acc.y *= sc;
        for (int j = lo; j < hi; ++j) {
            int s = csr[j];
            float nm = dinv[s] * dd;
            float2 v = hp[(size_t)s * 64 + lane];
            acc.x = fmaf(v.x, nm, acc.x);
            acc.y = fmaf(v.y, nm, acc.y);
        }
        float2 b = ((const float2*)bias)[lane];
        acc.x = fmaxf(acc.x + b.x, 0.f);
        acc.y = fmaxf(acc.y + b.y, 0.f);
        ((float2*)out)[(size_t)wid * 64 + lane] = acc;
    }
}

// ---------------- pool + fc ----------------
// pool: each block sums a PCH-node contiguous slice; batch is sorted, so flush
// to pool[g] via atomicAdd only at graph boundaries (~(N/PCH + NGRAPH) flushes).

__launch_bounds__(128)
__global__ void pool_kernel(const float* __restrict__ h, const int* __restrict__ batch,
                            float* __restrict__ pool, int N) {
    int c = threadIdx.x;              // dim 0..127
    int i0 = blockIdx.x * PCH;
    if (i0 >= N) return;
    int i1 = min(i0 + PCH, N);
    int g = batch[i0];
    float acc = 0.f;
#pragma unroll 4
    for (int i = i0; i < i1; ++i) {
        int gi = batch[i];
        if (gi != g) {                // wave-uniform branch
            atomicAdd(&pool[g * HID2 + c], acc);
            acc = 0.f; g = gi;
        }
        acc += h[(size_t)i * HID2 + c];
    }
    atomicAdd(&pool[g * HID2 + c], acc);
}

__device__ __forceinline__ int lower_bound_i(const int* __restrict__ a, int n, int key) {
    int lo = 0, hi = n;
    while (lo < hi) {
        int mid = (lo + hi) >> 1;
        if (a[mid] < key) lo = mid + 1; else hi = mid;
    }
    return lo;
}

__global__ void fc_kernel(const float* __restrict__ pool, const int* __restrict__ batch,
                          const float* __restrict__ Wfc, const float* __restrict__ bfc,
                          float* __restrict__ out, int N) {
    int t = threadIdx.x;  // 256 = 64 graphs * 4 outputs
    int g = t >> 2, o = t & 3;
    int lo = lower_bound_i(batch, N, g);
    int hi = lower_bound_i(batch, N, g + 1);
    float acc = 0.f;
#pragma unroll 8
    for (int c = 0; c < HID2; ++c)
        acc = fmaf(pool[g * HID2 + c], Wfc[c * OUT_DIM + o], acc);
    float inv = 1.0f / fmaxf((float)(hi - lo), 1.0f);
    out[g * OUT_DIM + o] = acc * inv + bfc[o];
}

extern "C" void kernel_launch(void* const* d_in, const int* in_sizes, int n_in,
                              void* d_out, int out_size, void* d_ws, size_t ws_size,
                              hipStream_t stream) {
    const float* x   = (const float*)d_in[0];
    const int* src   = (const int*)d_in[1];
    const int* dst   = (const int*)d_in[2];
    const int* batch = (const int*)d_in[3];
    const float* W1  = (const float*)d_in[4];
    const float* b1  = (const float*)d_in[5];
    const float* W2  = (const float*)d_in[6];
    const float* b2  = (const float*)d_in[7];
    const float* Wfc = (const float*)d_in[8];
    const float* bfc = (const float*)d_in[9];
    float* out = (float*)d_out;

    const int N = in_sizes[0] / IN_DIM;  // 50000
    const int E = in_sizes[1];           // 640000
    const int NB = (N + 255) / 256;      // scan blocks (196)

    // ---- workspace layout ----
    char* ws = (char*)d_ws;
    size_t off = 0;
    auto alloc = [&](size_t bytes) {
        char* p = ws + off;
        off = (off + bytes + 255) & ~(size_t)255;
        return p;
    };
    float* dinv   = (float*)alloc((size_t)N * 4);
    int*   count  = (int*)  alloc((size_t)N * 4);
    int*   cursor = (int*)  alloc((size_t)N * 4);
    int*   rowptr = (int*)  alloc((size_t)(N + 1) * 4);
    int*   bsums  = (int*)  alloc(256 * 4);
    int*   csr    = (int*)  alloc((size_t)E * 4);
    float* h1     = (float*)alloc((size_t)N * HID * 4);   // reused as h2 (N*HID2)
    float* a1     = (float*)alloc((size_t)N * HID * 4);   // reused as a2 (N*HID2)
    float* pool   = (float*)alloc((size_t)NGRAPH * HID2 * 4);
    float* h2 = h1;
    float* a2 = a1;

    // ---- CSR build (once; serves both layers) ----
    hipMemsetAsync(count, 0, (size_t)N * 4, stream);
    hist_kernel<<<(E + 255) / 256, 256, 0, stream>>>(dst, count, E);
    scan1_kernel<<<NB, 256, 0, stream>>>(count, bsums, N);
    scan2_kernel<<<1, 256, 0, stream>>>(bsums, NB);
    scan3_kernel<<<NB, 256, 0, stream>>>(count, bsums, rowptr, cursor, dinv, N, E);
    scatter_kernel<<<(E + 255) / 256, 256, 0, stream>>>(src, dst, cursor, csr, E);

    // ---- layer 1 ----
    gemm_kernel<IN_DIM><<<dim3(HID / 64, (N + 63) / 64), 256, 0, stream>>>(x, W1, h1, N, HID);
    agg_gather_kernel<HID><<<(N + 3) / 4, 256, 0, stream>>>(h1, dinv, rowptr, csr, b1, a1, N);

    // ---- layer 2 ----
    gemm_kernel<HID><<<dim3(HID2 / 64, (N + 63) / 64), 256, 0, stream>>>(a1, W2, h2, N, HID2);
    agg_gather_kernel<HID2><<<(N + 3) / 4, 256, 0, stream>>>(h2, dinv, rowptr, csr, b2, a2, N);

    // ---- pool + fc ----
    hipMemsetAsync(pool, 0, (size_t)NGRAPH * HID2 * 4, stream);
    pool_kernel<<<(N + PCH - 1) / PCH, HID2, 0, stream>>>(a2, batch, pool, N);
    fc_kernel<<<1, NGRAPH * OUT_DIM, 0, stream>>>(pool, batch, Wfc, bfc, out, N);
}